// Round 1
// baseline (201.567 us; speedup 1.0000x reference)
//
#include <hip/hip_runtime.h>
#include <hip/hip_bf16.h>
#include <math.h>

#define BB 512
#define SS 50
#define EE 128
#define HH 8
#define RR 32
#define NC 5

__device__ __forceinline__ void fma4(float4& a, float s, const float4& w) {
    a.x = fmaf(s, w.x, a.x);
    a.y = fmaf(s, w.y, a.y);
    a.z = fmaf(s, w.z, a.z);
    a.w = fmaf(s, w.w, a.w);
}

__device__ __forceinline__ float dot4(const float4& a, const float4& b) {
    return a.x*b.x + a.y*b.y + a.z*b.z + a.w*b.w;
}

// -------------------- Kernel 1: attention + wo --------------------
// one block per b, 256 threads
__global__ __launch_bounds__(256) void attn_kernel(
    const int* __restrict__ user, const int* __restrict__ item,
    const int* __restrict__ neighbor,
    const float* __restrict__ uet, const float* __restrict__ iet,
    const float* __restrict__ wq, const float* __restrict__ bq,
    const float* __restrict__ wk, const float* __restrict__ bk,
    const float* __restrict__ wv, const float* __restrict__ bv,
    const float* __restrict__ wo, const float* __restrict__ bo,
    float* __restrict__ ws_item, float* __restrict__ ws_ne2)
{
    __shared__ float ne[SS][EE];     // neighbor embeddings (then reused read-only)
    __shared__ float vbuf[SS][EE];   // v, then ctx
    __shared__ float ue[EE];
    __shared__ float qs[EE];
    __shared__ float attn_s[HH][SS]; // logits -> softmax
    __shared__ float maskadd[SS];

    const int b = blockIdx.x;
    const int t = threadIdx.x;

    // ---- phase 1: gathers ----
    if (t < EE) {
        ue[t] = uet[(size_t)user[b]*EE + t];
    } else {
        ws_item[(size_t)b*EE + (t - EE)] = iet[(size_t)item[b]*EE + (t - EE)];
    }
    for (int idx = t; idx < SS*(EE/4); idx += 256) {
        int s = idx >> 5, c = idx & 31;
        const float4* src = (const float4*)(uet + (size_t)neighbor[b*SS + s]*EE);
        ((float4*)&ne[s][0])[c] = src[c];
    }
    if (t < SS) maskadd[t] = (neighbor[b*SS + t] > 0) ? 0.f : -1e9f;
    __syncthreads();

    // ---- phase 2: q = ue @ wq + bq ----
    if (t < EE) {
        float acc = bq[t];
        #pragma unroll 4
        for (int e = 0; e < EE; ++e) acc = fmaf(ue[e], wq[e*EE + t], acc);
        qs[t] = acc;
    }
    __syncthreads();

    // ---- phase 3: k (folded into logits) and v ----
    {
        const int m  = t >> 7;        // 0 = k, 1 = v (wave-uniform)
        const int r  = t & 127;
        const int cg = r & 31;        // column group: output cols [cg*4, cg*4+3]
        const int sg = r >> 5;        // 0..3, s = i*4+sg
        const float4* w4p = (const float4*)(m ? wv : wk);

        float4 acc[13];
        #pragma unroll
        for (int i = 0; i < 13; ++i) acc[i] = make_float4(0.f,0.f,0.f,0.f);

        for (int e4 = 0; e4 < EE/4; ++e4) {
            float4 w0 = w4p[(e4*4 + 0)*(EE/4) + cg];
            float4 w1 = w4p[(e4*4 + 1)*(EE/4) + cg];
            float4 w2 = w4p[(e4*4 + 2)*(EE/4) + cg];
            float4 w3 = w4p[(e4*4 + 3)*(EE/4) + cg];
            #pragma unroll
            for (int i = 0; i < 13; ++i) {
                int s = i*4 + sg;
                if (s < SS) {
                    float4 nv = ((const float4*)&ne[s][0])[e4];
                    fma4(acc[i], nv.x, w0);
                    fma4(acc[i], nv.y, w1);
                    fma4(acc[i], nv.z, w2);
                    fma4(acc[i], nv.w, w3);
                }
            }
        }

        if (m == 0) {
            // k-half: add bias, dot with q, reduce 4 lanes -> logits[h][s]
            float4 q4  = ((const float4*)qs)[cg];
            float4 bk4 = ((const float4*)bk)[cg];
            #pragma unroll
            for (int i = 0; i < 13; ++i) {
                int s = i*4 + sg;
                if (s < SS) {   // wave-uniform guard
                    float4 kk;
                    kk.x = acc[i].x + bk4.x; kk.y = acc[i].y + bk4.y;
                    kk.z = acc[i].z + bk4.z; kk.w = acc[i].w + bk4.w;
                    float p = dot4(kk, q4);
                    p += __shfl_xor(p, 1);
                    p += __shfl_xor(p, 2);
                    if ((cg & 3) == 0) attn_s[cg >> 2][s] = p * 0.25f + maskadd[s];
                }
            }
        } else {
            float4 bv4 = ((const float4*)bv)[cg];
            #pragma unroll
            for (int i = 0; i < 13; ++i) {
                int s = i*4 + sg;
                if (s < SS) {
                    float4 vv;
                    vv.x = acc[i].x + bv4.x; vv.y = acc[i].y + bv4.y;
                    vv.z = acc[i].z + bv4.z; vv.w = acc[i].w + bv4.w;
                    ((float4*)&vbuf[s][0])[cg] = vv;
                }
            }
        }
    }
    __syncthreads();

    // ---- phase 4: softmax over s per head (one wave) ----
    if (t < 64) {
        int h = t >> 3, l = t & 7;
        float mx = -3e38f;
        #pragma unroll
        for (int i = 0; i < 7; ++i) { int s = i*8 + l; if (s < SS) mx = fmaxf(mx, attn_s[h][s]); }
        mx = fmaxf(mx, __shfl_xor(mx, 1));
        mx = fmaxf(mx, __shfl_xor(mx, 2));
        mx = fmaxf(mx, __shfl_xor(mx, 4));
        float ev[7]; float sm = 0.f;
        #pragma unroll
        for (int i = 0; i < 7; ++i) {
            int s = i*8 + l; ev[i] = 0.f;
            if (s < SS) { ev[i] = expf(attn_s[h][s] - mx); sm += ev[i]; }
        }
        sm += __shfl_xor(sm, 1);
        sm += __shfl_xor(sm, 2);
        sm += __shfl_xor(sm, 4);
        float inv = 1.f / sm;
        #pragma unroll
        for (int i = 0; i < 7; ++i) { int s = i*8 + l; if (s < SS) attn_s[h][s] = ev[i] * inv; }
    }
    __syncthreads();

    // ---- phase 5: ctx = attn * v (in place) ----
    for (int idx = t; idx < SS*(EE/4); idx += 256) {
        int s = idx >> 5, c = idx & 31;
        int h = c >> 2;
        float a = attn_s[h][s];
        float4 vv = ((float4*)&vbuf[s][0])[c];
        vv.x *= a; vv.y *= a; vv.z *= a; vv.w *= a;
        ((float4*)&vbuf[s][0])[c] = vv;
    }
    __syncthreads();

    // ---- phase 6: ne2 = ctx @ wo + bo -> global ws ----
    {
        const int cg = t & 31;
        const int sg = t >> 5;  // 0..7, s = i*8+sg
        const float4* w4p = (const float4*)wo;
        float4 acc[7];
        #pragma unroll
        for (int i = 0; i < 7; ++i) acc[i] = make_float4(0.f,0.f,0.f,0.f);

        for (int e4 = 0; e4 < EE/4; ++e4) {
            float4 w0 = w4p[(e4*4 + 0)*(EE/4) + cg];
            float4 w1 = w4p[(e4*4 + 1)*(EE/4) + cg];
            float4 w2 = w4p[(e4*4 + 2)*(EE/4) + cg];
            float4 w3 = w4p[(e4*4 + 3)*(EE/4) + cg];
            #pragma unroll
            for (int i = 0; i < 7; ++i) {
                int s = i*8 + sg;
                if (s < SS) {
                    float4 nv = ((const float4*)&vbuf[s][0])[e4];
                    fma4(acc[i], nv.x, w0);
                    fma4(acc[i], nv.y, w1);
                    fma4(acc[i], nv.z, w2);
                    fma4(acc[i], nv.w, w3);
                }
            }
        }
        float4 bo4 = ((const float4*)bo)[cg];
        #pragma unroll
        for (int i = 0; i < 7; ++i) {
            int s = i*8 + sg;
            if (s < SS) {
                float4 o;
                o.x = acc[i].x + bo4.x; o.y = acc[i].y + bo4.y;
                o.z = acc[i].z + bo4.z; o.w = acc[i].w + bo4.w;
                ((float4*)ws_ne2)[((size_t)b*SS + s)*(EE/4) + cg] = o;
            }
        }
    }
}

// -------------------- Kernel 2: region gather + dots (BW-bound) --------------------
// one block per (b,s), 256 threads; thread (r = t>>3, l = t&7)
__global__ __launch_bounds__(256) void region_kernel(
    const int* __restrict__ neighbor, const int* __restrict__ seq,
    const float* __restrict__ ui_lcu, const float* __restrict__ iu_lcu,
    const float* __restrict__ ws_item, const float* __restrict__ ws_ne2,
    float* __restrict__ ws_rating)
{
    __shared__ float ner[EE], ier[EE];
    const int bs = blockIdx.x;
    const int b  = bs / SS;
    const int t  = threadIdx.x;

    if (t < EE) ner[t] = ws_ne2[(size_t)bs*EE + t];
    else        ier[t - EE] = ws_item[(size_t)b*EE + (t - EE)];

    const int nb = neighbor[bs];
    const int j  = seq[bs];
    const float w = (nb > 0) ? 1.f : 0.f;
    __syncthreads();

    const int r = t >> 3, l = t & 7;
    const float4* kiu = (const float4*)(iu_lcu + ((size_t)j*RR + r)*EE);
    const float4* kui = (const float4*)(ui_lcu + ((size_t)j*RR + r)*EE);
    const float4* n4 = (const float4*)ner;
    const float4* i4 = (const float4*)ier;

    float np_ = 0.f, ip_ = 0.f;
    #pragma unroll
    for (int i = 0; i < 4; ++i) {
        int c = l + 8*i;          // float4 index within the 128-elem row
        float4 a = kiu[c];
        float4 x = n4[c];
        np_ += dot4(a, x);
        float4 g = kui[c];
        float4 y = i4[c];
        ip_ += dot4(g, y);
    }
    np_ += __shfl_xor(np_, 1); np_ += __shfl_xor(np_, 2); np_ += __shfl_xor(np_, 4);
    ip_ += __shfl_xor(ip_, 1); ip_ += __shfl_xor(ip_, 2); ip_ += __shfl_xor(ip_, 4);

    if (l == 0) ws_rating[(size_t)bs*RR + r] = np_ * ip_ * w;
}

// -------------------- Kernel 3: max over s, FC, softmax --------------------
__global__ __launch_bounds__(64) void head_kernel(
    const float* __restrict__ ws_rating,
    const float* __restrict__ fc_w, const float* __restrict__ fc_b,
    float* __restrict__ out)
{
    __shared__ float urv[RR];
    __shared__ float lg[NC];
    const int b = blockIdx.x, t = threadIdx.x;

    if (t < RR) {
        float m = -3e38f;
        const float* p = ws_rating + (size_t)b*SS*RR + t;
        for (int s = 0; s < SS; ++s) m = fmaxf(m, p[s*RR]);
        urv[t] = m;
    }
    __syncthreads();
    if (t < NC) {
        float acc = fc_b[t];
        #pragma unroll
        for (int r = 0; r < RR; ++r) acc = fmaf(urv[r], fc_w[r*NC + t], acc);
        lg[t] = acc;
    }
    __syncthreads();
    if (t < NC) {
        float mx = lg[0];
        #pragma unroll
        for (int c = 1; c < NC; ++c) mx = fmaxf(mx, lg[c]);
        float sm = 0.f;
        #pragma unroll
        for (int c = 0; c < NC; ++c) sm += expf(lg[c] - mx);
        out[b*NC + t] = expf(lg[t] - mx) / sm;
    }
}

extern "C" void kernel_launch(void* const* d_in, const int* in_sizes, int n_in,
                              void* d_out, int out_size, void* d_ws, size_t ws_size,
                              hipStream_t stream) {
    const int*   user     = (const int*)d_in[0];
    const int*   item     = (const int*)d_in[1];
    const int*   neighbor = (const int*)d_in[2];
    const int*   seq      = (const int*)d_in[3];
    const float* uet      = (const float*)d_in[4];
    const float* iet      = (const float*)d_in[5];
    const float* ui_lcu   = (const float*)d_in[6];
    const float* iu_lcu   = (const float*)d_in[7];
    const float* wq = (const float*)d_in[8];   const float* bq = (const float*)d_in[9];
    const float* wk = (const float*)d_in[10];  const float* bk = (const float*)d_in[11];
    const float* wv = (const float*)d_in[12];  const float* bv = (const float*)d_in[13];
    const float* wo = (const float*)d_in[14];  const float* bo = (const float*)d_in[15];
    const float* fcw = (const float*)d_in[16]; const float* fcb = (const float*)d_in[17];

    float* ws = (float*)d_ws;
    float* ws_item   = ws;                                    // B*E
    float* ws_ne2    = ws_item + (size_t)BB*EE;               // B*S*E
    float* ws_rating = ws_ne2  + (size_t)BB*SS*EE;            // B*S*R
    float* out = (float*)d_out;

    hipLaunchKernelGGL(attn_kernel, dim3(BB), dim3(256), 0, stream,
                       user, item, neighbor, uet, iet,
                       wq, bq, wk, bk, wv, bv, wo, bo, ws_item, ws_ne2);
    hipLaunchKernelGGL(region_kernel, dim3(BB*SS), dim3(256), 0, stream,
                       neighbor, seq, ui_lcu, iu_lcu, ws_item, ws_ne2, ws_rating);
    hipLaunchKernelGGL(head_kernel, dim3(BB), dim3(64), 0, stream,
                       ws_rating, fcw, fcb, out);
}